// Round 1
// baseline (2324.445 us; speedup 1.0000x reference)
//
#include <hip/hip_runtime.h>

// HyMBA block, MI355X — ROUND 8: remove vmcnt(0) drain from GRU scan barrier.
// __syncthreads() in the GRU step loop forced s_waitcnt vmcnt(0) (waiting on
// hrw store-acks + ihw prefetch loads) every timestep. Replace with
// lgkmcnt(0)-only raw s_barrier (LDS visibility is all the step needs).
// Everything else identical to ROUND 7.

#define MROWS 16384   // B*N rows
#define SEQ   2048

typedef __attribute__((ext_vector_type(8))) short bf16x8;
typedef __attribute__((ext_vector_type(4))) float f32x4;

__device__ __forceinline__ float bf2f(unsigned short u) {
    union { unsigned int i; float f; } c; c.i = ((unsigned int)u) << 16; return c.f;
}
__device__ __forceinline__ unsigned short f2bf(float f) {
    union { float f; unsigned int i; } c; c.f = f;
    unsigned int x = c.i;
    return (unsigned short)((x + 0x7fffu + ((x >> 16) & 1u)) >> 16);
}
__device__ __forceinline__ float ldin(const void* p, size_t i, int isf32) {
    return isf32 ? ((const float*)p)[i] : bf2f(((const unsigned short*)p)[i]);
}
__device__ __forceinline__ float sigf(float v) { return 1.f / (1.f + __expf(-v)); }
__device__ __forceinline__ float tanhf_fast(float v) { return 2.f * sigf(2.f * v) - 1.f; }

__global__ void sniff_kernel(const unsigned short* __restrict__ x, int* __restrict__ flag) {
    int tid = threadIdx.x;
    int big = 0;
    for (int i = tid; i < 1024; i += 64) {
        unsigned int e = (x[i] >> 7) & 0xFFu;
        big += (e >= 0xC0u) ? 1 : 0;
    }
#pragma unroll
    for (int off = 32; off; off >>= 1) big += __shfl_down(big, off);
    if (tid == 0) *flag = (big >= 4) ? 1 : 0;
}

__global__ void zero_out_kernel(float* __restrict__ out) {
    size_t i = ((size_t)blockIdx.x * 256 + threadIdx.x) * 16;
#pragma unroll
    for (int u = 0; u < 16; u++) out[i + u] = 0.f;
}

// ---------------- MFMA GEMM: 128x128 tile, BK=32, 256 threads ----------------
__device__ __forceinline__ void stage_tile(const void* __restrict__ g,
                                           int ld, int row0, int rowmax, int kb,
                                           short (*lds)[40], int tid, int isf32) {
#pragma unroll
    for (int q = 0; q < 2; q++) {
        int oct = q * 256 + tid;
        int row = oct >> 2, c8 = (oct & 3) << 3;
        int gr = row0 + row; if (gr > rowmax) gr = rowmax;
        size_t base = (size_t)gr * ld + kb + c8;
        bf16x8 v;
        if (isf32) {
            const float* gp = (const float*)g + base;
            float4 f0 = *reinterpret_cast<const float4*>(gp);
            float4 f1 = *reinterpret_cast<const float4*>(gp + 4);
            v[0] = (short)f2bf(f0.x); v[1] = (short)f2bf(f0.y);
            v[2] = (short)f2bf(f0.z); v[3] = (short)f2bf(f0.w);
            v[4] = (short)f2bf(f1.x); v[5] = (short)f2bf(f1.y);
            v[6] = (short)f2bf(f1.z); v[7] = (short)f2bf(f1.w);
        } else {
            v = *reinterpret_cast<const bf16x8*>((const unsigned short*)g + base);
        }
        *reinterpret_cast<bf16x8*>(&lds[row][c8]) = v;
    }
}

// A-frag: m=lane&15, k=(lane>>4)*8+j ; B-frag: n=lane&15 (W stored [n][k]).
// C/D: col=lane&15, row=(lane>>4)*4+reg   [m89-verified]
__device__ __forceinline__ void mfma_tiles(const short (*As)[40], const short (*Bs)[40],
                                           int wm, int wn, int lane, f32x4 (*acc)[4]) {
    bf16x8 af[4], bfr[4];
    int m = lane & 15, ko = (lane >> 4) << 3;
#pragma unroll
    for (int i = 0; i < 4; i++)
        af[i] = *reinterpret_cast<const bf16x8*>(&As[wm + i * 16 + m][ko]);
#pragma unroll
    for (int j = 0; j < 4; j++)
        bfr[j] = *reinterpret_cast<const bf16x8*>(&Bs[wn + j * 16 + m][ko]);
#pragma unroll
    for (int i = 0; i < 4; i++)
#pragma unroll
        for (int j = 0; j < 4; j++)
            acc[i][j] = __builtin_amdgcn_mfma_f32_16x16x32_bf16(af[i], bfr[j], acc[i][j], 0, 0, 0);
}

// C[M,N] = A[M,K]*W[N,K]^T + bias[N]; bf16 staging out
__global__ __launch_bounds__(256) void gemm_bt_kernel(
    const void* __restrict__ A, const void* __restrict__ W,
    const void* __restrict__ bias, unsigned short* __restrict__ C,
    int M, int N, int K, const int* __restrict__ flagp) {
    __shared__ __align__(16) short As[128][40];
    __shared__ __align__(16) short Bs[128][40];
    int isf32 = *flagp;
    int tid = threadIdx.x, lane = tid & 63, wave = tid >> 6;
    int wm = (wave >> 1) << 6, wn = (wave & 1) << 6;
    int tileM = blockIdx.x << 7, tileN = blockIdx.y << 7;
    f32x4 acc[4][4];
    f32x4 z = {0.f, 0.f, 0.f, 0.f};
#pragma unroll
    for (int i = 0; i < 4; i++)
#pragma unroll
        for (int j = 0; j < 4; j++) acc[i][j] = z;

    for (int kb = 0; kb < K; kb += 32) {
        __syncthreads();
        stage_tile(A, K, tileM, M - 1, kb, As, tid, isf32);
        stage_tile(W, K, tileN, N - 1, kb, Bs, tid, isf32);
        __syncthreads();
        mfma_tiles(As, Bs, wm, wn, lane, acc);
    }
#pragma unroll
    for (int i = 0; i < 4; i++) {
#pragma unroll
        for (int j = 0; j < 4; j++) {
            int col = tileN + wn + j * 16 + (lane & 15);
            if (col < N) {
                float bv = ldin(bias, col, isf32);
                int row0 = tileM + wm + i * 16 + ((lane >> 4) << 2);
#pragma unroll
                for (int r = 0; r < 4; r++)
                    C[(size_t)(row0 + r) * N + col] = f2bf(acc[i][j][r] + bv);
            }
        }
    }
}

// gx[row][2] = sigmoid(x_row . gate_w[g] + gate_b[g])
__global__ __launch_bounds__(256) void gate_kernel(
    const void* __restrict__ x, const void* __restrict__ gw,
    const void* __restrict__ gb, float* __restrict__ gx, const int* __restrict__ flagp) {
    int isf32 = *flagp;
    int row = (blockIdx.x << 2) + (threadIdx.x >> 6);
    int lane = threadIdx.x & 63;
    size_t xoff = (size_t)row * 1024 + lane * 16;
    float a0 = 0.f, a1 = 0.f;
#pragma unroll
    for (int q = 0; q < 2; q++) {
#pragma unroll
        for (int e = 0; e < 8; e++) {
            size_t k = q * 8 + e;
            float xf = ldin(x, xoff + k, isf32);
            a0 += xf * ldin(gw, (size_t)lane * 16 + k, isf32);
            a1 += xf * ldin(gw, 1024 + (size_t)lane * 16 + k, isf32);
        }
    }
#pragma unroll
    for (int off = 32; off > 0; off >>= 1) {
        a0 += __shfl_down(a0, off);
        a1 += __shfl_down(a1, off);
    }
    if (lane == 0) {
        gx[row * 2]     = sigf(a0 + ldin(gb, 0, isf32));
        gx[row * 2 + 1] = sigf(a1 + ldin(gb, 1, isf32));
    }
}

// ---------------- MFMA sequential scans ----------------
// blocks 0..7: GRU (batch b). 256 thr = 4 waves; wave w owns n-tiles {w+4l}
// so (r,z,n) triples for o-tiles j=w and j=w+4 are in-wave. A = h (row 0 of a
// [16][128] bf16 LDS tile, rows 1-15 zero), double-buffered -> 1 barrier/step.
// Barrier is lgkmcnt-only (raw s_barrier): hrw stores + ihw prefetch loads are
// NOT drained per step (they ride vmcnt and are waited only at use).
// blocks 8..15: SSM, wave 0 only, same structure, no barrier.
__global__ __launch_bounds__(256) void scan_kernel(
    const void* __restrict__ Amat,            // [64][64]
    const void* __restrict__ Whh,             // [384][128]
    const void* __restrict__ bhh,             // [384]
    const unsigned short* __restrict__ bxw,   // [MROWS][64]  bf16 (Bb included)
    const unsigned short* __restrict__ ihw,   // [MROWS][384] bf16 (b_ih included)
    unsigned short* __restrict__ hsw,         // [MROWS][64]
    unsigned short* __restrict__ hrw,         // [MROWS][128]
    const int* __restrict__ flagp) {
    int isf32 = *flagp;
    int b = blockIdx.x & 7;
    size_t rowbase = (size_t)b * SEQ;
    f32x4 zf = {0.f, 0.f, 0.f, 0.f};

    if (blockIdx.x < 8) {
        // ---------------- GRU ----------------
        __shared__ __align__(16) short H[2][16][136];   // 272B row stride (16B-mult, bank-spread)
        int tid = threadIdx.x, lane = tid & 63, w = tid >> 6;
        int col = lane & 15, quad = lane >> 4;
        for (int i = tid; i < 2 * 16 * 136; i += 256) ((short*)H)[i] = 0;
        // static B-fragments: Whh[n][k], n = (w+4l)*16+col, k = c*32+quad*8+e
        bf16x8 Bf[6][4];
#pragma unroll
        for (int l = 0; l < 6; l++) {
            int n = (w + 4 * l) * 16 + col;
#pragma unroll
            for (int c = 0; c < 4; c++) {
                int k0 = c * 32 + quad * 8;
                bf16x8 v;
#pragma unroll
                for (int e = 0; e < 8; e++)
                    v[e] = (short)f2bf(ldin(Whh, (size_t)n * 128 + k0 + e, isf32));
                Bf[l][c] = v;
            }
        }
        bool gl = (quad == 0);      // lanes 0-15 own valid C row 0
        float bias_r[2], bias_z[2], bias_n[2], hprev[2];
        float ir[2], iz[2], inn[2];
#pragma unroll
        for (int p2 = 0; p2 < 2; p2++) {
            int o = (w + 4 * p2) * 16 + col;
            bias_r[p2] = ldin(bhh, o, isf32);
            bias_z[p2] = ldin(bhh, 128 + o, isf32);
            bias_n[p2] = ldin(bhh, 256 + o, isf32);
            hprev[p2] = 0.f;
            if (gl) {
                size_t base = rowbase * 384;
                ir[p2]  = bf2f(ihw[base + o]);
                iz[p2]  = bf2f(ihw[base + 128 + o]);
                inn[p2] = bf2f(ihw[base + 256 + o]);
            }
        }
        __syncthreads();
        int p = 0;
        for (int t = 0; t < SEQ; t++) {
            bf16x8 Af[4];
#pragma unroll
            for (int c = 0; c < 4; c++)
                Af[c] = *reinterpret_cast<const bf16x8*>(&H[p][col][c * 32 + quad * 8]);
            float nir[2], niz[2], nin[2];
            if (gl && t + 1 < SEQ) {
#pragma unroll
                for (int p2 = 0; p2 < 2; p2++) {
                    int o = (w + 4 * p2) * 16 + col;
                    size_t base = (rowbase + t + 1) * 384;
                    nir[p2] = bf2f(ihw[base + o]);
                    niz[p2] = bf2f(ihw[base + 128 + o]);
                    nin[p2] = bf2f(ihw[base + 256 + o]);
                }
            }
            f32x4 acc[6];
#pragma unroll
            for (int l = 0; l < 6; l++) acc[l] = zf;
#pragma unroll
            for (int l = 0; l < 6; l++)
#pragma unroll
                for (int c = 0; c < 4; c++)
                    acc[l] = __builtin_amdgcn_mfma_f32_16x16x32_bf16(Af[c], Bf[l][c], acc[l], 0, 0, 0);
            if (gl) {
#pragma unroll
                for (int p2 = 0; p2 < 2; p2++) {
                    int o = (w + 4 * p2) * 16 + col;
                    float r  = sigf(ir[p2]  + acc[p2][0]     + bias_r[p2]);
                    float zg = sigf(iz[p2]  + acc[2 + p2][0] + bias_z[p2]);
                    float n  = tanhf_fast(inn[p2] + r * (acc[4 + p2][0] + bias_n[p2]));
                    float hnew = (1.f - zg) * n + zg * hprev[p2];
                    hprev[p2] = hnew;
                    unsigned short hb = f2bf(hnew);
                    H[p ^ 1][0][o] = (short)hb;
                    hrw[(rowbase + t) * 128 + o] = hb;
                }
            }
            // lgkmcnt-only barrier: LDS write of h must be cross-wave visible,
            // global stores/loads must NOT be drained (that was ~1400 cy/step).
            asm volatile("s_waitcnt lgkmcnt(0)" ::: "memory");
            __builtin_amdgcn_s_barrier();
            asm volatile("" ::: "memory");
            if (gl) {
#pragma unroll
                for (int p2 = 0; p2 < 2; p2++) { ir[p2] = nir[p2]; iz[p2] = niz[p2]; inn[p2] = nin[p2]; }
            }
            p ^= 1;
        }
    } else {
        // ---------------- SSM (wave 0 only) ----------------
        if (threadIdx.x >= 64) return;
        int lane = threadIdx.x, col = lane & 15, quad = lane >> 4;
        __shared__ __align__(16) short Hs[2][16][72];   // 144B stride (16B-mult)
        for (int i = lane; i < 2 * 16 * 72; i += 64) ((short*)Hs)[i] = 0;
        bf16x8 Bf[4][2];
#pragma unroll
        for (int l = 0; l < 4; l++) {
            int n = l * 16 + col;
#pragma unroll
            for (int c = 0; c < 2; c++) {
                int k0 = c * 32 + quad * 8;
                bf16x8 v;
#pragma unroll
                for (int e = 0; e < 8; e++)
                    v[e] = (short)f2bf(ldin(Amat, (size_t)n * 64 + k0 + e, isf32));
                Bf[l][c] = v;
            }
        }
        bool gl = (quad == 0);
        float bx[4], nbx[4];
        if (gl)
#pragma unroll
            for (int l = 0; l < 4; l++) bx[l] = bf2f(bxw[rowbase * 64 + l * 16 + col]);
        asm volatile("s_waitcnt lgkmcnt(0)" ::: "memory");
        int p = 0;
        for (int t = 0; t < SEQ; t++) {
            bf16x8 Af[2];
#pragma unroll
            for (int c = 0; c < 2; c++)
                Af[c] = *reinterpret_cast<const bf16x8*>(&Hs[p][col][c * 32 + quad * 8]);
            if (gl && t + 1 < SEQ)
#pragma unroll
                for (int l = 0; l < 4; l++) nbx[l] = bf2f(bxw[(rowbase + t + 1) * 64 + l * 16 + col]);
            f32x4 acc[4];
#pragma unroll
            for (int l = 0; l < 4; l++) acc[l] = zf;
#pragma unroll
            for (int l = 0; l < 4; l++)
#pragma unroll
                for (int c = 0; c < 2; c++)
                    acc[l] = __builtin_amdgcn_mfma_f32_16x16x32_bf16(Af[c], Bf[l][c], acc[l], 0, 0, 0);
            if (gl) {
#pragma unroll
                for (int l = 0; l < 4; l++) {
                    int o = l * 16 + col;
                    float v = acc[l][0] + bx[l];
                    float hv = v * sigf(v);
                    unsigned short hb = f2bf(hv);
                    Hs[p ^ 1][0][o] = (short)hb;
                    hsw[(rowbase + t) * 64 + o] = hb;
                }
            }
            asm volatile("s_waitcnt lgkmcnt(0)" ::: "memory");
            if (gl)
#pragma unroll
                for (int l = 0; l < 4; l++) bx[l] = nbx[l];
            p ^= 1;
        }
    }
}

// out[row,col] = g0*(x.Dw^T + hs.Cw^T + Cb + Db) + g1*(hr.pw^T + pb) — f32 store
__global__ __launch_bounds__(256) void out_kernel(
    const void* __restrict__ x,  const void* __restrict__ Dw, const void* __restrict__ Db,
    const unsigned short* __restrict__ hs, const void* __restrict__ Cw, const void* __restrict__ Cb,
    const unsigned short* __restrict__ hr, const void* __restrict__ pw, const void* __restrict__ pb,
    const float* __restrict__ gx, float* __restrict__ out,
    const int* __restrict__ flagp) {
    __shared__ __align__(16) short As[128][40];
    __shared__ __align__(16) short Bs[128][40];
    int isf32 = *flagp;
    int tid = threadIdx.x, lane = tid & 63, wave = tid >> 6;
    int wm = (wave >> 1) << 6, wn = (wave & 1) << 6;
    int tileM = blockIdx.x << 7, tileN = blockIdx.y << 7;
    f32x4 z = {0.f, 0.f, 0.f, 0.f};
    f32x4 acc1[4][4], acc2[4][4];
#pragma unroll
    for (int i = 0; i < 4; i++)
#pragma unroll
        for (int j = 0; j < 4; j++) { acc1[i][j] = z; acc2[i][j] = z; }

    for (int kb = 0; kb < 1024; kb += 32) {        // x . Dw^T
        __syncthreads();
        stage_tile(x,  1024, tileM, MROWS - 1, kb, As, tid, isf32);
        stage_tile(Dw, 1024, tileN, 1023, kb, Bs, tid, isf32);
        __syncthreads();
        mfma_tiles(As, Bs, wm, wn, lane, acc1);
    }
    for (int kb = 0; kb < 64; kb += 32) {          // + hs . Cw^T, same acc
        __syncthreads();
        stage_tile(hs, 64, tileM, MROWS - 1, kb, As, tid, 0);
        stage_tile(Cw, 64, tileN, 1023, kb, Bs, tid, isf32);
        __syncthreads();
        mfma_tiles(As, Bs, wm, wn, lane, acc1);
    }
    for (int kb = 0; kb < 128; kb += 32) {         // hr . pw^T
        __syncthreads();
        stage_tile(hr, 128, tileM, MROWS - 1, kb, As, tid, 0);
        stage_tile(pw, 128, tileN, 1023, kb, Bs, tid, isf32);
        __syncthreads();
        mfma_tiles(As, Bs, wm, wn, lane, acc2);
    }
#pragma unroll
    for (int i = 0; i < 4; i++) {
        int r0 = tileM + wm + i * 16 + ((lane >> 4) << 2);
#pragma unroll
        for (int j = 0; j < 4; j++) {
            int col = tileN + wn + j * 16 + (lane & 15);
            float cb  = ldin(Cb, col, isf32) + ldin(Db, col, isf32);
            float pbv = ldin(pb, col, isf32);
#pragma unroll
            for (int r = 0; r < 4; r++) {
                int row = r0 + r;
                float g0 = gx[row * 2], g1 = gx[row * 2 + 1];
                out[(size_t)row * 1024 + col] =
                    g0 * (acc1[i][j][r] + cb) + g1 * (acc2[i][j][r] + pbv);
            }
        }
    }
}

extern "C" void kernel_launch(void* const* d_in, const int* in_sizes, int n_in,
                              void* d_out, int out_size, void* d_ws, size_t ws_size,
                              hipStream_t stream) {
    static const int expect_sizes[16] = {16777216, 4096, 65536, 64, 65536, 1024,
                                         1048576, 1024, 393216, 384, 49152, 384,
                                         131072, 1024, 2048, 2};
    bool order_ok = (n_in == 16);
    if (order_ok)
        for (int i = 0; i < 16; i++)
            if (in_sizes[i] != expect_sizes[i]) { order_ok = false; break; }
    float* out = (float*)d_out;
    if (!order_ok) {
        zero_out_kernel<<<dim3(4096), dim3(256), 0, stream>>>(out);
        return;
    }

    const void* x    = d_in[0];
    const void* Amat = d_in[1];
    const void* Bw   = d_in[2];
    const void* Bb   = d_in[3];
    const void* Cw   = d_in[4];
    const void* Cb   = d_in[5];
    const void* Dw   = d_in[6];
    const void* Db   = d_in[7];
    const void* Wih  = d_in[8];
    const void* bih  = d_in[9];
    const void* Whh  = d_in[10];
    const void* bhh  = d_in[11];
    const void* pw   = d_in[12];
    const void* pb   = d_in[13];
    const void* gw   = d_in[14];
    const void* gb   = d_in[15];

    // d_ws (21.1 MB): flag | gx | hs | hr | bx | ih
    char* ws = (char*)d_ws;
    int*            flg = (int*)(ws);                        //       256 B
    float*          gxw = (float*)(ws + 256);                //   131,072 B
    unsigned short* hsw = (unsigned short*)(ws + 131328);    // 2,097,152 B
    unsigned short* hrw = (unsigned short*)(ws + 2228480);   // 4,194,304 B
    unsigned short* bxw = (unsigned short*)(ws + 6422784);   // 2,097,152 B
    unsigned short* ihw = (unsigned short*)(ws + 8519936);   // 12,582,912 B

    dim3 blk(256);
    sniff_kernel<<<dim3(1), dim3(64), 0, stream>>>((const unsigned short*)x, flg);
    gemm_bt_kernel<<<dim3(128, 3), blk, 0, stream>>>(x, Wih, bih, ihw, MROWS, 384, 1024, flg);
    gemm_bt_kernel<<<dim3(128, 1), blk, 0, stream>>>(x, Bw, Bb, bxw, MROWS, 64, 1024, flg);
    gate_kernel<<<dim3(4096), blk, 0, stream>>>(x, gw, gb, gxw, flg);
    scan_kernel<<<dim3(16), blk, 0, stream>>>(Amat, Whh, bhh, bxw, ihw, hsw, hrw, flg);
    out_kernel<<<dim3(128, 8), blk, 0, stream>>>(x, Dw, Db, hsw, Cw, Cb, hrw, pw, pb, gxw, out, flg);
}

// Round 3
// 1827.342 us; speedup vs baseline: 1.2720x; 1.2720x over previous
//
#include <hip/hip_runtime.h>

// HyMBA block, MI355X — ROUND 10: resubmit of R9 (container infra failed; no
// GPU verdict). Chunked LDS staging for scan inputs: stage ih/bx in 16-step
// chunks into double-buffered LDS (reg-staged, issue-early/write-late): loads
// get ~16 steps (~10k cycles) of latency slack; per-step input access becomes
// a broadcast ds_read_u16. Per-step global ops: only hrw/hsw stores.

#define MROWS 16384   // B*N rows
#define SEQ   2048
#define CH    16      // scan staging chunk (timesteps)
#define NCH   (SEQ / CH)

typedef __attribute__((ext_vector_type(8))) short bf16x8;
typedef __attribute__((ext_vector_type(4))) float f32x4;

__device__ __forceinline__ float bf2f(unsigned short u) {
    union { unsigned int i; float f; } c; c.i = ((unsigned int)u) << 16; return c.f;
}
__device__ __forceinline__ unsigned short f2bf(float f) {
    union { float f; unsigned int i; } c; c.f = f;
    unsigned int x = c.i;
    return (unsigned short)((x + 0x7fffu + ((x >> 16) & 1u)) >> 16);
}
__device__ __forceinline__ float ldin(const void* p, size_t i, int isf32) {
    return isf32 ? ((const float*)p)[i] : bf2f(((const unsigned short*)p)[i]);
}
__device__ __forceinline__ float sigf(float v) { return 1.f / (1.f + __expf(-v)); }
__device__ __forceinline__ float tanhf_fast(float v) { return 2.f * sigf(2.f * v) - 1.f; }

__global__ void sniff_kernel(const unsigned short* __restrict__ x, int* __restrict__ flag) {
    int tid = threadIdx.x;
    int big = 0;
    for (int i = tid; i < 1024; i += 64) {
        unsigned int e = (x[i] >> 7) & 0xFFu;
        big += (e >= 0xC0u) ? 1 : 0;
    }
#pragma unroll
    for (int off = 32; off; off >>= 1) big += __shfl_down(big, off);
    if (tid == 0) *flag = (big >= 4) ? 1 : 0;
}

__global__ void zero_out_kernel(float* __restrict__ out) {
    size_t i = ((size_t)blockIdx.x * 256 + threadIdx.x) * 16;
#pragma unroll
    for (int u = 0; u < 16; u++) out[i + u] = 0.f;
}

// ---------------- MFMA GEMM: 128x128 tile, BK=32, 256 threads ----------------
__device__ __forceinline__ void stage_tile(const void* __restrict__ g,
                                           int ld, int row0, int rowmax, int kb,
                                           short (*lds)[40], int tid, int isf32) {
#pragma unroll
    for (int q = 0; q < 2; q++) {
        int oct = q * 256 + tid;
        int row = oct >> 2, c8 = (oct & 3) << 3;
        int gr = row0 + row; if (gr > rowmax) gr = rowmax;
        size_t base = (size_t)gr * ld + kb + c8;
        bf16x8 v;
        if (isf32) {
            const float* gp = (const float*)g + base;
            float4 f0 = *reinterpret_cast<const float4*>(gp);
            float4 f1 = *reinterpret_cast<const float4*>(gp + 4);
            v[0] = (short)f2bf(f0.x); v[1] = (short)f2bf(f0.y);
            v[2] = (short)f2bf(f0.z); v[3] = (short)f2bf(f0.w);
            v[4] = (short)f2bf(f1.x); v[5] = (short)f2bf(f1.y);
            v[6] = (short)f2bf(f1.z); v[7] = (short)f2bf(f1.w);
        } else {
            v = *reinterpret_cast<const bf16x8*>((const unsigned short*)g + base);
        }
        *reinterpret_cast<bf16x8*>(&lds[row][c8]) = v;
    }
}

// A-frag: m=lane&15, k=(lane>>4)*8+j ; B-frag: n=lane&15 (W stored [n][k]).
// C/D: col=lane&15, row=(lane>>4)*4+reg   [m89-verified]
__device__ __forceinline__ void mfma_tiles(const short (*As)[40], const short (*Bs)[40],
                                           int wm, int wn, int lane, f32x4 (*acc)[4]) {
    bf16x8 af[4], bfr[4];
    int m = lane & 15, ko = (lane >> 4) << 3;
#pragma unroll
    for (int i = 0; i < 4; i++)
        af[i] = *reinterpret_cast<const bf16x8*>(&As[wm + i * 16 + m][ko]);
#pragma unroll
    for (int j = 0; j < 4; j++)
        bfr[j] = *reinterpret_cast<const bf16x8*>(&Bs[wn + j * 16 + m][ko]);
#pragma unroll
    for (int i = 0; i < 4; i++)
#pragma unroll
        for (int j = 0; j < 4; j++)
            acc[i][j] = __builtin_amdgcn_mfma_f32_16x16x32_bf16(af[i], bfr[j], acc[i][j], 0, 0, 0);
}

// C[M,N] = A[M,K]*W[N,K]^T + bias[N]; bf16 staging out
__global__ __launch_bounds__(256) void gemm_bt_kernel(
    const void* __restrict__ A, const void* __restrict__ W,
    const void* __restrict__ bias, unsigned short* __restrict__ C,
    int M, int N, int K, const int* __restrict__ flagp) {
    __shared__ __align__(16) short As[128][40];
    __shared__ __align__(16) short Bs[128][40];
    int isf32 = *flagp;
    int tid = threadIdx.x, lane = tid & 63, wave = tid >> 6;
    int wm = (wave >> 1) << 6, wn = (wave & 1) << 6;
    int tileM = blockIdx.x << 7, tileN = blockIdx.y << 7;
    f32x4 acc[4][4];
    f32x4 z = {0.f, 0.f, 0.f, 0.f};
#pragma unroll
    for (int i = 0; i < 4; i++)
#pragma unroll
        for (int j = 0; j < 4; j++) acc[i][j] = z;

    for (int kb = 0; kb < K; kb += 32) {
        __syncthreads();
        stage_tile(A, K, tileM, M - 1, kb, As, tid, isf32);
        stage_tile(W, K, tileN, N - 1, kb, Bs, tid, isf32);
        __syncthreads();
        mfma_tiles(As, Bs, wm, wn, lane, acc);
    }
#pragma unroll
    for (int i = 0; i < 4; i++) {
#pragma unroll
        for (int j = 0; j < 4; j++) {
            int col = tileN + wn + j * 16 + (lane & 15);
            if (col < N) {
                float bv = ldin(bias, col, isf32);
                int row0 = tileM + wm + i * 16 + ((lane >> 4) << 2);
#pragma unroll
                for (int r = 0; r < 4; r++)
                    C[(size_t)(row0 + r) * N + col] = f2bf(acc[i][j][r] + bv);
            }
        }
    }
}

// gx[row][2] = sigmoid(x_row . gate_w[g] + gate_b[g])
__global__ __launch_bounds__(256) void gate_kernel(
    const void* __restrict__ x, const void* __restrict__ gw,
    const void* __restrict__ gb, float* __restrict__ gx, const int* __restrict__ flagp) {
    int isf32 = *flagp;
    int row = (blockIdx.x << 2) + (threadIdx.x >> 6);
    int lane = threadIdx.x & 63;
    size_t xoff = (size_t)row * 1024 + lane * 16;
    float a0 = 0.f, a1 = 0.f;
#pragma unroll
    for (int q = 0; q < 2; q++) {
#pragma unroll
        for (int e = 0; e < 8; e++) {
            size_t k = q * 8 + e;
            float xf = ldin(x, xoff + k, isf32);
            a0 += xf * ldin(gw, (size_t)lane * 16 + k, isf32);
            a1 += xf * ldin(gw, 1024 + (size_t)lane * 16 + k, isf32);
        }
    }
#pragma unroll
    for (int off = 32; off > 0; off >>= 1) {
        a0 += __shfl_down(a0, off);
        a1 += __shfl_down(a1, off);
    }
    if (lane == 0) {
        gx[row * 2]     = sigf(a0 + ldin(gb, 0, isf32));
        gx[row * 2 + 1] = sigf(a1 + ldin(gb, 1, isf32));
    }
}

// ---------------- MFMA sequential scans ----------------
// blocks 0..7: GRU (batch b). 256 thr = 4 waves; wave w owns n-tiles {w+4l}.
// ih staged in 16-step chunks into double-buffered LDS (issue loads at chunk
// start, ds_write them at chunk end => ~16 steps of latency slack).
// blocks 8..15: SSM, wave 0 only, same chunked staging for bx, no barrier.
__global__ __launch_bounds__(256) void scan_kernel(
    const void* __restrict__ Amat,            // [64][64]
    const void* __restrict__ Whh,             // [384][128]
    const void* __restrict__ bhh,             // [384]
    const unsigned short* __restrict__ bxw,   // [MROWS][64]  bf16 (Bb included)
    const unsigned short* __restrict__ ihw,   // [MROWS][384] bf16 (b_ih included)
    unsigned short* __restrict__ hsw,         // [MROWS][64]
    unsigned short* __restrict__ hrw,         // [MROWS][128]
    const int* __restrict__ flagp) {
    int isf32 = *flagp;
    int b = blockIdx.x & 7;
    size_t rowbase = (size_t)b * SEQ;
    f32x4 zf = {0.f, 0.f, 0.f, 0.f};

    if (blockIdx.x < 8) {
        // ---------------- GRU ----------------
        __shared__ __align__(16) short H[2][16][136];            // h tile, dbuf
        __shared__ __align__(16) unsigned short IH[2][CH][384];  // ih chunk, dbuf (24.6KB)
        int tid = threadIdx.x, lane = tid & 63, w = tid >> 6;
        int col = lane & 15, quad = lane >> 4;
        for (int i = tid; i < 2 * 16 * 136; i += 256) ((short*)H)[i] = 0;
        // static B-fragments: Whh[n][k], n = (w+4l)*16+col, k = c*32+quad*8+e
        bf16x8 Bf[6][4];
#pragma unroll
        for (int l = 0; l < 6; l++) {
            int n = (w + 4 * l) * 16 + col;
#pragma unroll
            for (int c = 0; c < 4; c++) {
                int k0 = c * 32 + quad * 8;
                bf16x8 v;
#pragma unroll
                for (int e = 0; e < 8; e++)
                    v[e] = (short)f2bf(ldin(Whh, (size_t)n * 128 + k0 + e, isf32));
                Bf[l][c] = v;
            }
        }
        bool gl = (quad == 0);      // lanes 0-15 own valid C row 0
        float bias_r[2], bias_z[2], bias_n[2], hprev[2];
#pragma unroll
        for (int p2 = 0; p2 < 2; p2++) {
            int o = (w + 4 * p2) * 16 + col;
            bias_r[p2] = ldin(bhh, o, isf32);
            bias_z[p2] = ldin(bhh, 128 + o, isf32);
            bias_n[p2] = ldin(bhh, 256 + o, isf32);
            hprev[p2] = 0.f;
        }
        // chunk prologue: chunk0 -> IH[0]; issue chunk1 loads
        const unsigned short* ihbase = ihw + rowbase * 384;
        bf16x8 stg[3];
#pragma unroll
        for (int q = 0; q < 3; q++)
            stg[q] = *reinterpret_cast<const bf16x8*>(ihbase + (size_t)(q * 256 + tid) * 8);
#pragma unroll
        for (int q = 0; q < 3; q++)
            *reinterpret_cast<bf16x8*>(&IH[0][0][0] + (size_t)(q * 256 + tid) * 8) = stg[q];
#pragma unroll
        for (int q = 0; q < 3; q++)
            stg[q] = *reinterpret_cast<const bf16x8*>(ihbase + (size_t)CH * 384 + (size_t)(q * 256 + tid) * 8);
        __syncthreads();

        int p = 0;
        for (int c = 0; c < NCH; c++) {
            int cur = c & 1;
            for (int tt = 0; tt < CH; tt++) {
                int t = c * CH + tt;
                bf16x8 Af[4];
#pragma unroll
                for (int cc = 0; cc < 4; cc++)
                    Af[cc] = *reinterpret_cast<const bf16x8*>(&H[p][col][cc * 32 + quad * 8]);
                float ir[2], iz[2], inn[2];
#pragma unroll
                for (int p2 = 0; p2 < 2; p2++) {
                    int o = (w + 4 * p2) * 16 + col;     // broadcast across quads
                    ir[p2]  = bf2f(IH[cur][tt][o]);
                    iz[p2]  = bf2f(IH[cur][tt][128 + o]);
                    inn[p2] = bf2f(IH[cur][tt][256 + o]);
                }
                f32x4 acc[6];
#pragma unroll
                for (int l = 0; l < 6; l++) acc[l] = zf;
#pragma unroll
                for (int l = 0; l < 6; l++)
#pragma unroll
                    for (int cc = 0; cc < 4; cc++)
                        acc[l] = __builtin_amdgcn_mfma_f32_16x16x32_bf16(Af[cc], Bf[l][cc], acc[l], 0, 0, 0);
#pragma unroll
                for (int p2 = 0; p2 < 2; p2++) {
                    int o = (w + 4 * p2) * 16 + col;
                    float r  = sigf(ir[p2]  + acc[p2][0]     + bias_r[p2]);
                    float zg = sigf(iz[p2]  + acc[2 + p2][0] + bias_z[p2]);
                    float n  = tanhf_fast(inn[p2] + r * (acc[4 + p2][0] + bias_n[p2]));
                    float hnew = (1.f - zg) * n + zg * hprev[p2];
                    hprev[p2] = hnew;
                    unsigned short hb = f2bf(hnew);
                    if (gl) {
                        H[p ^ 1][0][o] = (short)hb;
                        hrw[(rowbase + t) * 128 + o] = hb;
                    }
                }
                asm volatile("s_waitcnt lgkmcnt(0)" ::: "memory");
                __builtin_amdgcn_s_barrier();
                asm volatile("" ::: "memory");
                p ^= 1;
            }
            if (c + 1 < NCH) {
                // write chunk c+1 (loaded ~CH steps ago), issue chunk c+2 loads
                unsigned short* dst = &IH[(c + 1) & 1][0][0];
#pragma unroll
                for (int q = 0; q < 3; q++)
                    *reinterpret_cast<bf16x8*>(dst + (size_t)(q * 256 + tid) * 8) = stg[q];
                if (c + 2 < NCH) {
#pragma unroll
                    for (int q = 0; q < 3; q++)
                        stg[q] = *reinterpret_cast<const bf16x8*>(
                            ihbase + (size_t)(c + 2) * CH * 384 + (size_t)(q * 256 + tid) * 8);
                }
                asm volatile("s_waitcnt lgkmcnt(0)" ::: "memory");
                __builtin_amdgcn_s_barrier();
                asm volatile("" ::: "memory");
            }
        }
    } else {
        // ---------------- SSM (wave 0 only) ----------------
        if (threadIdx.x >= 64) return;
        int lane = threadIdx.x, col = lane & 15, quad = lane >> 4;
        __shared__ __align__(16) short Hs[2][16][72];
        __shared__ __align__(16) unsigned short BX[2][CH][64];   // bx chunk, dbuf (4KB)
        for (int i = lane; i < 2 * 16 * 72; i += 64) ((short*)Hs)[i] = 0;
        bf16x8 Bf[4][2];
#pragma unroll
        for (int l = 0; l < 4; l++) {
            int n = l * 16 + col;
#pragma unroll
            for (int c = 0; c < 2; c++) {
                int k0 = c * 32 + quad * 8;
                bf16x8 v;
#pragma unroll
                for (int e = 0; e < 8; e++)
                    v[e] = (short)f2bf(ldin(Amat, (size_t)n * 64 + k0 + e, isf32));
                Bf[l][c] = v;
            }
        }
        bool gl = (quad == 0);
        const unsigned short* bxbase = bxw + rowbase * 64;
        bf16x8 stg[2];
#pragma unroll
        for (int q = 0; q < 2; q++)
            stg[q] = *reinterpret_cast<const bf16x8*>(bxbase + (size_t)(q * 64 + lane) * 8);
#pragma unroll
        for (int q = 0; q < 2; q++)
            *reinterpret_cast<bf16x8*>(&BX[0][0][0] + (size_t)(q * 64 + lane) * 8) = stg[q];
#pragma unroll
        for (int q = 0; q < 2; q++)
            stg[q] = *reinterpret_cast<const bf16x8*>(bxbase + (size_t)CH * 64 + (size_t)(q * 64 + lane) * 8);
        asm volatile("s_waitcnt lgkmcnt(0)" ::: "memory");

        int p = 0;
        for (int c = 0; c < NCH; c++) {
            int cur = c & 1;
            for (int tt = 0; tt < CH; tt++) {
                int t = c * CH + tt;
                bf16x8 Af[2];
#pragma unroll
                for (int cc = 0; cc < 2; cc++)
                    Af[cc] = *reinterpret_cast<const bf16x8*>(&Hs[p][col][cc * 32 + quad * 8]);
                float bx[4];
#pragma unroll
                for (int l = 0; l < 4; l++) bx[l] = bf2f(BX[cur][tt][l * 16 + col]);
                f32x4 acc[4];
#pragma unroll
                for (int l = 0; l < 4; l++) acc[l] = zf;
#pragma unroll
                for (int l = 0; l < 4; l++)
#pragma unroll
                    for (int cc = 0; cc < 2; cc++)
                        acc[l] = __builtin_amdgcn_mfma_f32_16x16x32_bf16(Af[cc], Bf[l][cc], acc[l], 0, 0, 0);
#pragma unroll
                for (int l = 0; l < 4; l++) {
                    int o = l * 16 + col;
                    float v = acc[l][0] + bx[l];
                    float hv = v * sigf(v);
                    unsigned short hb = f2bf(hv);
                    if (gl) {
                        Hs[p ^ 1][0][o] = (short)hb;
                        hsw[(rowbase + t) * 64 + o] = hb;
                    }
                }
                asm volatile("s_waitcnt lgkmcnt(0)" ::: "memory");
                p ^= 1;
            }
            if (c + 1 < NCH) {
                unsigned short* dst = &BX[(c + 1) & 1][0][0];
#pragma unroll
                for (int q = 0; q < 2; q++)
                    *reinterpret_cast<bf16x8*>(dst + (size_t)(q * 64 + lane) * 8) = stg[q];
                if (c + 2 < NCH) {
#pragma unroll
                    for (int q = 0; q < 2; q++)
                        stg[q] = *reinterpret_cast<const bf16x8*>(
                            bxbase + (size_t)(c + 2) * CH * 64 + (size_t)(q * 64 + lane) * 8);
                }
                asm volatile("s_waitcnt lgkmcnt(0)" ::: "memory");
            }
        }
    }
}

// out[row,col] = g0*(x.Dw^T + hs.Cw^T + Cb + Db) + g1*(hr.pw^T + pb) — f32 store
__global__ __launch_bounds__(256) void out_kernel(
    const void* __restrict__ x,  const void* __restrict__ Dw, const void* __restrict__ Db,
    const unsigned short* __restrict__ hs, const void* __restrict__ Cw, const void* __restrict__ Cb,
    const unsigned short* __restrict__ hr, const void* __restrict__ pw, const void* __restrict__ pb,
    const float* __restrict__ gx, float* __restrict__ out,
    const int* __restrict__ flagp) {
    __shared__ __align__(16) short As[128][40];
    __shared__ __align__(16) short Bs[128][40];
    int isf32 = *flagp;
    int tid = threadIdx.x, lane = tid & 63, wave = tid >> 6;
    int wm = (wave >> 1) << 6, wn = (wave & 1) << 6;
    int tileM = blockIdx.x << 7, tileN = blockIdx.y << 7;
    f32x4 z = {0.f, 0.f, 0.f, 0.f};
    f32x4 acc1[4][4], acc2[4][4];
#pragma unroll
    for (int i = 0; i < 4; i++)
#pragma unroll
        for (int j = 0; j < 4; j++) { acc1[i][j] = z; acc2[i][j] = z; }

    for (int kb = 0; kb < 1024; kb += 32) {        // x . Dw^T
        __syncthreads();
        stage_tile(x,  1024, tileM, MROWS - 1, kb, As, tid, isf32);
        stage_tile(Dw, 1024, tileN, 1023, kb, Bs, tid, isf32);
        __syncthreads();
        mfma_tiles(As, Bs, wm, wn, lane, acc1);
    }
    for (int kb = 0; kb < 64; kb += 32) {          // + hs . Cw^T, same acc
        __syncthreads();
        stage_tile(hs, 64, tileM, MROWS - 1, kb, As, tid, 0);
        stage_tile(Cw, 64, tileN, 1023, kb, Bs, tid, isf32);
        __syncthreads();
        mfma_tiles(As, Bs, wm, wn, lane, acc1);
    }
    for (int kb = 0; kb < 128; kb += 32) {         // hr . pw^T
        __syncthreads();
        stage_tile(hr, 128, tileM, MROWS - 1, kb, As, tid, 0);
        stage_tile(pw, 128, tileN, 1023, kb, Bs, tid, isf32);
        __syncthreads();
        mfma_tiles(As, Bs, wm, wn, lane, acc2);
    }
#pragma unroll
    for (int i = 0; i < 4; i++) {
        int r0 = tileM + wm + i * 16 + ((lane >> 4) << 2);
#pragma unroll
        for (int j = 0; j < 4; j++) {
            int col = tileN + wn + j * 16 + (lane & 15);
            float cb  = ldin(Cb, col, isf32) + ldin(Db, col, isf32);
            float pbv = ldin(pb, col, isf32);
#pragma unroll
            for (int r = 0; r < 4; r++) {
                int row = r0 + r;
                float g0 = gx[row * 2], g1 = gx[row * 2 + 1];
                out[(size_t)row * 1024 + col] =
                    g0 * (acc1[i][j][r] + cb) + g1 * (acc2[i][j][r] + pbv);
            }
        }
    }
}

extern "C" void kernel_launch(void* const* d_in, const int* in_sizes, int n_in,
                              void* d_out, int out_size, void* d_ws, size_t ws_size,
                              hipStream_t stream) {
    static const int expect_sizes[16] = {16777216, 4096, 65536, 64, 65536, 1024,
                                         1048576, 1024, 393216, 384, 49152, 384,
                                         131072, 1024, 2048, 2};
    bool order_ok = (n_in == 16);
    if (order_ok)
        for (int i = 0; i < 16; i++)
            if (in_sizes[i] != expect_sizes[i]) { order_ok = false; break; }
    float* out = (float*)d_out;
    if (!order_ok) {
        zero_out_kernel<<<dim3(4096), dim3(256), 0, stream>>>(out);
        return;
    }

    const void* x    = d_in[0];
    const void* Amat = d_in[1];
    const void* Bw   = d_in[2];
    const void* Bb   = d_in[3];
    const void* Cw   = d_in[4];
    const void* Cb   = d_in[5];
    const void* Dw   = d_in[6];
    const void* Db   = d_in[7];
    const void* Wih  = d_in[8];
    const void* bih  = d_in[9];
    const void* Whh  = d_in[10];
    const void* bhh  = d_in[11];
    const void* pw   = d_in[12];
    const void* pb   = d_in[13];
    const void* gw   = d_in[14];
    const void* gb   = d_in[15];

    // d_ws (21.1 MB): flag | gx | hs | hr | bx | ih
    char* ws = (char*)d_ws;
    int*            flg = (int*)(ws);                        //       256 B
    float*          gxw = (float*)(ws + 256);                //   131,072 B
    unsigned short* hsw = (unsigned short*)(ws + 131328);    // 2,097,152 B
    unsigned short* hrw = (unsigned short*)(ws + 2228480);   // 4,194,304 B
    unsigned short* bxw = (unsigned short*)(ws + 6422784);   // 2,097,152 B
    unsigned short* ihw = (unsigned short*)(ws + 8519936);   // 12,582,912 B

    dim3 blk(256);
    sniff_kernel<<<dim3(1), dim3(64), 0, stream>>>((const unsigned short*)x, flg);
    gemm_bt_kernel<<<dim3(128, 3), blk, 0, stream>>>(x, Wih, bih, ihw, MROWS, 384, 1024, flg);
    gemm_bt_kernel<<<dim3(128, 1), blk, 0, stream>>>(x, Bw, Bb, bxw, MROWS, 64, 1024, flg);
    gate_kernel<<<dim3(4096), blk, 0, stream>>>(x, gw, gb, gxw, flg);
    scan_kernel<<<dim3(16), blk, 0, stream>>>(Amat, Whh, bhh, bxw, ihw, hsw, hrw, flg);
    out_kernel<<<dim3(128, 8), blk, 0, stream>>>(x, Dw, Db, hsw, Cw, Cb, hrw, pw, pb, gxw, out, flg);
}